// Round 11
// baseline (278.707 us; speedup 1.0000x reference)
//
#include <hip/hip_runtime.h>
#include <cstdint>
#include <cstddef>

#define TT   512   // sequence length
#define MT   16    // batch per block (one MFMA N-tile)
#define OUTN 30    // output features
#define RD   8     // ring depth (slots), power of 2

typedef __attribute__((ext_vector_type(8))) short short8;
typedef __attribute__((ext_vector_type(4))) float floatx4;

#define NLOG2E  (-1.4426950408889634f)   // sigmoid rows: z' = -log2e * z
#define N2LOG2E (-2.8853900817779268f)   // tanh rows:    z' = -2log2e * z

static __device__ __forceinline__ float rcpf(float x) { return __builtin_amdgcn_rcpf(x); }
static __device__ __forceinline__ float ex2(float x)  { return __builtin_amdgcn_exp2f(x); }

// single-instruction RNE f32->bf16
static __device__ __forceinline__ unsigned short cvt_bf16(float f) {
    unsigned int r;
    asm("v_cvt_pk_bf16_f32 %0, %1, %2" : "=v"(r) : "v"(f), "v"(f));
    return (unsigned short)r;
}
static __device__ __forceinline__ unsigned short to_bf16(float f) {  // exact RNE (weight preload)
    union { float f; unsigned int u; } v; v.f = f;
    return (unsigned short)((v.u + 0x7FFFu + ((v.u >> 16) & 1u)) >> 16);
}

static __device__ __forceinline__ float gate_scale(int gate) {
    return (gate == 2) ? N2LOG2E : NLOG2E;
}

// Load 8 consecutive bf16 weights from row-major [128][32], row-permuted and pre-scaled.
// perm row R holds original row (R&3)*32 + (R>>2): order [i0,f0,g0,o0, i1,...]
static __device__ __forceinline__ short8 load_frag_perm(const float* __restrict__ W, int arow, int k0) {
    int gate = arow & 3;
    int orig = gate * 32 + (arow >> 2);
    float s = gate_scale(gate);
    const float* p = W + orig * 32 + k0;
    short8 v;
#pragma unroll
    for (int e = 0; e < 8; ++e) v[e] = (short)to_bf16(s * p[e]);
    return v;
}
static __device__ __forceinline__ short8 load_frag_plain(const float* __restrict__ W, int row, int k0) {
    const float* p = W + row * 32 + k0;
    short8 v;
#pragma unroll
    for (int e = 0; e < 8; ++e) v[e] = (short)to_bf16(p[e]);
    return v;
}

// Two-element cell math (7 trans each), stage-interleaved.
static __device__ __forceinline__ void gates2(floatx4 z0, floatx4 z1,
                                              float& c0, float& c1,
                                              unsigned short& h0b, unsigned short& h1b) {
    float Di0 = 1.0f + ex2(z0[0]), Df0 = 1.0f + ex2(z0[1]);
    float Dg0 = 1.0f + ex2(z0[2]), Do0 = 1.0f + ex2(z0[3]);
    float Di1 = 1.0f + ex2(z1[0]), Df1 = 1.0f + ex2(z1[1]);
    float Dg1 = 1.0f + ex2(z1[2]), Do1 = 1.0f + ex2(z1[3]);
    float m10 = Di0 * Df0, tt0 = Df0 * Dg0, ss0 = Di0 * Dg0;
    float m11 = Di1 * Df1, tt1 = Df1 * Dg1, ss1 = Di1 * Dg1;
    float r30 = rcpf(m10 * Dg0);
    float r31 = rcpf(m11 * Dg1);
    float i0 = tt0 * r30, f0 = ss0 * r30;
    float i1 = tt1 * r31, f1 = ss1 * r31;
    float tg0 = __builtin_fmaf(m10 + m10, r30, -1.0f);
    float tg1 = __builtin_fmaf(m11 + m11, r31, -1.0f);
    c0 = __builtin_fmaf(f0, c0, i0 * tg0);
    c1 = __builtin_fmaf(f1, c1, i1 * tg1);
    float Dc0 = 1.0f + ex2(N2LOG2E * c0);
    float Dc1 = 1.0f + ex2(N2LOG2E * c1);
    float r20 = rcpf(Do0 * Dc0);
    float r21 = rcpf(Do1 * Dc1);
    h0b = cvt_bf16((2.0f - Dc0) * r20);
    h1b = cvt_bf16((2.0f - Dc1) * r21);
}

// Grid: 256 blocks (one 16-batch tile). Block: 768 threads = 12 waves =
// 3 groups x 4 waves. Group g runs layer g's ENTIRE 512-step recurrence with
// its OWN LDS sense-barrier — the three groups' barriers are independent, so
// one group's post-barrier latency window is filled by the other groups'
// issue on the same SIMD (3 waves/SIMD, one per group).
// Wave w4 in a group owns row-tiles {2w4, 2w4+1} = units {8w4+q, 8w4+4+q}
// per lane -> 2 cell elems, 14 trans. Layers chained by LDS rings (depth 8)
// with acquire/release progress counters:
//   G0 step t: [t>=8: wait prog1 >= t-7]   read h0(t-1), write h0(t)
//   G1 step t: wait prog0 >= t+1, [prog2 >= t-7]; read h1(t-1), h0(t)
//   G2 step t: wait prog1 >= t+1;           read h2(t-1), h1(t)
// Acyclic waits + co-resident waves => deadlock-free. Slot -1 pre-zeroed.
__global__ __launch_bounds__(768, 1) void lstm_fused(
    const float* __restrict__ x,
    const float* __restrict__ Wih0, const float* __restrict__ Whh0,
    const float* __restrict__ bih0, const float* __restrict__ bhh0,
    const float* __restrict__ Wih1, const float* __restrict__ Whh1,
    const float* __restrict__ bih1, const float* __restrict__ bhh1,
    const float* __restrict__ Wih2, const float* __restrict__ Whh2,
    const float* __restrict__ bih2, const float* __restrict__ bhh2,
    const float* __restrict__ W2,   const float* __restrict__ b2,
    float* __restrict__ out)
{
    __shared__ float xs[MT][TT + 4];                 // 33 KB
    __shared__ unsigned short r0[RD][4][MT][8];      // 8 KB each
    __shared__ unsigned short r1[RD][4][MT][8];
    __shared__ unsigned short r2[RD][4][MT][8];
    __shared__ int arr3[3];                          // group arrive counters
    __shared__ int prog3[3];                         // published progress

    const int tid = (int)threadIdx.x;
    const int wv  = tid >> 6;          // 0..11
    const int grp = wv >> 2;           // 0,1,2 = layer
    const int w4  = wv & 3;            // wave-in-group
    const int l   = tid & 63;
    const int b   = l & 15;
    const int q   = l >> 4;
    const int k0  = q * 8;
    const int bt  = (int)blockIdx.x;

    if (tid < 3) { arr3[tid] = 0; prog3[tid] = 0; }
    // zero slot RD-1 of each ring (holds h(-1) = 0)
    for (int i = tid; i < 4 * MT * 8; i += 768) {
        ((unsigned short*)r0)[(RD - 1) * 512 + i] = 0;
        ((unsigned short*)r1)[(RD - 1) * 512 + i] = 0;
        ((unsigned short*)r2)[(RD - 1) * 512 + i] = 0;
    }
    // stage x tile [16][512]
    {
        const floatx4* xg = (const floatx4*)(x + (size_t)bt * MT * TT);
        for (int idx = tid; idx < MT * TT / 4; idx += 768) {
            int row = idx >> 7, c4 = idx & 127;
            *(floatx4*)&xs[row][c4 * 4] = xg[idx];
        }
    }
    __syncthreads();   // rings zeroed, x staged; ONLY block-wide barrier

    auto waitprog = [&](int g, int v) {
        while (__hip_atomic_load(&prog3[g], __ATOMIC_ACQUIRE,
                                 __HIP_MEMORY_SCOPE_WORKGROUP) < v)
            __builtin_amdgcn_s_sleep(1);
    };
    // group barrier + publish progress (release chain: ds writes -> arrive
    // (acq_rel) -> spin (acquire) -> publish (release) -> consumer acquire)
    auto gbar_pub = [&](int g, int t) {
        if (l == 0)
            __hip_atomic_fetch_add(&arr3[g], 1, __ATOMIC_ACQ_REL,
                                   __HIP_MEMORY_SCOPE_WORKGROUP);
        int tgt = 4 * (t + 1);
        while (__hip_atomic_load(&arr3[g], __ATOMIC_ACQUIRE,
                                 __HIP_MEMORY_SCOPE_WORKGROUP) < tgt)
            __builtin_amdgcn_s_sleep(1);
        if (w4 == 0 && l == 0)
            __hip_atomic_store(&prog3[g], t + 1, __ATOMIC_RELEASE,
                               __HIP_MEMORY_SCOPE_WORKGROUP);
    };

    if (grp == 0) {
        // ---- layer 0 engine: rank-1 input + self-recurrence ----
        short8 wf[2]; floatx4 bc[2]; float wx[2][4]; float c[2] = {0.f, 0.f};
#pragma unroll
        for (int j = 0; j < 2; ++j) {
            wf[j] = load_frag_perm(Whh0, 16 * (2 * w4 + j) + b, k0);
            int u = 8 * w4 + 4 * j + q;
#pragma unroll
            for (int r = 0; r < 4; ++r) {
                int row = r * 32 + u;
                float s = gate_scale(r);
                wx[j][r] = s * Wih0[row];
                bc[j][r] = s * (bih0[row] + bhh0[row]);
            }
        }
        for (int t = 0; t < TT; ++t) {
            if (t >= RD) waitprog(1, t - RD + 1);      // ring overwrite guard
            short8 bh = *(const short8*)&r0[(t - 1) & (RD - 1)][q][b][0];
            float xv = xs[b][t];
            floatx4 cx0, cx1;
#pragma unroll
            for (int r = 0; r < 4; ++r) {
                cx0[r] = __builtin_fmaf(xv, wx[0][r], bc[0][r]);
                cx1[r] = __builtin_fmaf(xv, wx[1][r], bc[1][r]);
            }
            floatx4 z0 = __builtin_amdgcn_mfma_f32_16x16x32_bf16(wf[0], bh, cx0, 0, 0, 0);
            floatx4 z1 = __builtin_amdgcn_mfma_f32_16x16x32_bf16(wf[1], bh, cx1, 0, 0, 0);
            unsigned short ha, hb;
            gates2(z0, z1, c[0], c[1], ha, hb);
            r0[t & (RD - 1)][w4][b][q]     = ha;
            r0[t & (RD - 1)][w4][b][q + 4] = hb;
            gbar_pub(0, t);
        }
    } else if (grp == 1) {
        // ---- layer 1 engine ----
        short8 whf[2], wif[2]; floatx4 bc[2]; float c[2] = {0.f, 0.f};
#pragma unroll
        for (int j = 0; j < 2; ++j) {
            whf[j] = load_frag_perm(Whh1, 16 * (2 * w4 + j) + b, k0);
            wif[j] = load_frag_perm(Wih1, 16 * (2 * w4 + j) + b, k0);
            int u = 8 * w4 + 4 * j + q;
#pragma unroll
            for (int r = 0; r < 4; ++r) {
                int row = r * 32 + u;
                float s = gate_scale(r);
                bc[j][r] = s * (bih1[row] + bhh1[row]);
            }
        }
        for (int t = 0; t < TT; ++t) {
            waitprog(0, t + 1);                        // h0(t) ready
            if (t >= RD) waitprog(2, t - RD + 1);      // ring overwrite guard
            short8 bown = *(const short8*)&r1[(t - 1) & (RD - 1)][q][b][0];
            short8 bcrs = *(const short8*)&r0[t & (RD - 1)][q][b][0];
            floatx4 z0 = __builtin_amdgcn_mfma_f32_16x16x32_bf16(whf[0], bown, bc[0], 0, 0, 0);
            floatx4 z1 = __builtin_amdgcn_mfma_f32_16x16x32_bf16(whf[1], bown, bc[1], 0, 0, 0);
            z0 = __builtin_amdgcn_mfma_f32_16x16x32_bf16(wif[0], bcrs, z0, 0, 0, 0);
            z1 = __builtin_amdgcn_mfma_f32_16x16x32_bf16(wif[1], bcrs, z1, 0, 0, 0);
            unsigned short ha, hb;
            gates2(z0, z1, c[0], c[1], ha, hb);
            r1[t & (RD - 1)][w4][b][q]     = ha;
            r1[t & (RD - 1)][w4][b][q + 4] = hb;
            gbar_pub(1, t);
        }
    } else {
        // ---- layer 2 engine + final projection ----
        short8 whf[2], wif[2]; floatx4 bc[2]; float c[2] = {0.f, 0.f};
#pragma unroll
        for (int j = 0; j < 2; ++j) {
            whf[j] = load_frag_perm(Whh2, 16 * (2 * w4 + j) + b, k0);
            wif[j] = load_frag_perm(Wih2, 16 * (2 * w4 + j) + b, k0);
            int u = 8 * w4 + 4 * j + q;
#pragma unroll
            for (int r = 0; r < 4; ++r) {
                int row = r * 32 + u;
                float s = gate_scale(r);
                bc[j][r] = s * (bih2[row] + bhh2[row]);
            }
        }
        short8 w2f = {};
        floatx4 b2c = {0.f, 0.f, 0.f, 0.f};
        if (w4 < 2) {
            int rrow = 16 * w4 + b;
            w2f = load_frag_plain(W2, rrow < OUTN ? rrow : OUTN - 1, k0);
#pragma unroll
            for (int r = 0; r < 4; ++r) {
                int rr = 16 * w4 + 4 * q + r;
                b2c[r] = (rr < OUTN) ? b2[rr] : 0.0f;
            }
        }
        for (int t = 0; t < TT; ++t) {
            waitprog(1, t + 1);                        // h1(t) ready
            short8 bown = *(const short8*)&r2[(t - 1) & (RD - 1)][q][b][0];
            short8 bcrs = *(const short8*)&r1[t & (RD - 1)][q][b][0];
            floatx4 z0 = __builtin_amdgcn_mfma_f32_16x16x32_bf16(whf[0], bown, bc[0], 0, 0, 0);
            floatx4 z1 = __builtin_amdgcn_mfma_f32_16x16x32_bf16(whf[1], bown, bc[1], 0, 0, 0);
            z0 = __builtin_amdgcn_mfma_f32_16x16x32_bf16(wif[0], bcrs, z0, 0, 0, 0);
            z1 = __builtin_amdgcn_mfma_f32_16x16x32_bf16(wif[1], bcrs, z1, 0, 0, 0);
            unsigned short ha, hb;
            gates2(z0, z1, c[0], c[1], ha, hb);
            r2[t & (RD - 1)][w4][b][q]     = ha;
            r2[t & (RD - 1)][w4][b][q + 4] = hb;
            gbar_pub(2, t);
        }
        // projection: out = h2(511) @ W2^T + b2 (waves 0,1 of this group)
        if (w4 < 2) {
            short8 bh2 = *(const short8*)&r2[(TT - 1) & (RD - 1)][q][b][0];
            floatx4 zo = __builtin_amdgcn_mfma_f32_16x16x32_bf16(w2f, bh2, b2c, 0, 0, 0);
#pragma unroll
            for (int r = 0; r < 4; ++r) {
                int rr = 16 * w4 + 4 * q + r;
                if (rr < OUTN)
                    out[(size_t)(bt * MT + b) * OUTN + rr] = zo[r];
            }
        }
    }
}

extern "C" void kernel_launch(void* const* d_in, const int* in_sizes, int n_in,
                              void* d_out, int out_size, void* d_ws, size_t ws_size,
                              hipStream_t stream) {
    const float* x    = (const float*)d_in[0];
    const float* Wih0 = (const float*)d_in[1];
    const float* Whh0 = (const float*)d_in[2];
    const float* bih0 = (const float*)d_in[3];
    const float* bhh0 = (const float*)d_in[4];
    const float* Wih1 = (const float*)d_in[5];
    const float* Whh1 = (const float*)d_in[6];
    const float* bih1 = (const float*)d_in[7];
    const float* bhh1 = (const float*)d_in[8];
    const float* Wih2 = (const float*)d_in[9];
    const float* Whh2 = (const float*)d_in[10];
    const float* bih2 = (const float*)d_in[11];
    const float* bhh2 = (const float*)d_in[12];
    const float* W2   = (const float*)d_in[13];
    const float* b2   = (const float*)d_in[14];
    float* out = (float*)d_out;

    dim3 grid(4096 / MT);   // 256 blocks, 1/CU
    dim3 block(768);        // 12 waves = 3 groups x 4 waves = 3/SIMD
    hipLaunchKernelGGL(lstm_fused, grid, block, 0, stream,
                       x, Wih0, Whh0, bih0, bhh0,
                       Wih1, Whh1, bih1, bhh1,
                       Wih2, Whh2, bih2, bhh2, W2, b2, out);
}

// Round 12
// 240.061 us; speedup vs baseline: 1.1610x; 1.1610x over previous
//
#include <hip/hip_runtime.h>
#include <cstdint>
#include <cstddef>

#define TT   512   // sequence length
#define MT   16    // batch per block (one MFMA N-tile)
#define OUTN 30    // output features

typedef __attribute__((ext_vector_type(8))) short short8;
typedef __attribute__((ext_vector_type(4))) float floatx4;

#define NLOG2E  (-1.4426950408889634f)   // sigmoid rows: z' = -log2e * z
#define N2LOG2E (-2.8853900817779268f)   // tanh rows:    z' = -2log2e * z

static __device__ __forceinline__ float rcpf(float x) { return __builtin_amdgcn_rcpf(x); }
static __device__ __forceinline__ float ex2(float x)  { return __builtin_amdgcn_exp2f(x); }

// single-instruction RNE f32->bf16
static __device__ __forceinline__ unsigned short cvt_bf16(float f) {
    unsigned int r;
    asm("v_cvt_pk_bf16_f32 %0, %1, %2" : "=v"(r) : "v"(f), "v"(f));
    return (unsigned short)r;
}
static __device__ __forceinline__ unsigned short to_bf16(float f) {  // exact RNE (weight preload)
    union { float f; unsigned int u; } v; v.f = f;
    return (unsigned short)((v.u + 0x7FFFu + ((v.u >> 16) & 1u)) >> 16);
}

// gate scale by PERMUTED row's gate index: rows [i,f,g,o] -> i,f,o: -log2e ; g: -2log2e
static __device__ __forceinline__ float gate_scale(int gate) {
    return (gate == 2) ? N2LOG2E : NLOG2E;
}

// Load 8 consecutive bf16 weights from row-major [128][32], row-permuted and pre-scaled.
// perm row R holds original row (R&3)*32 + (R>>2): order [i0,f0,g0,o0, i1,...]
static __device__ __forceinline__ short8 load_frag_perm(const float* __restrict__ W, int arow, int k0) {
    int gate = arow & 3;
    int orig = gate * 32 + (arow >> 2);
    float s = gate_scale(gate);
    const float* p = W + orig * 32 + k0;
    short8 v;
#pragma unroll
    for (int e = 0; e < 8; ++e) v[e] = (short)to_bf16(s * p[e]);
    return v;
}
static __device__ __forceinline__ short8 load_frag_plain(const float* __restrict__ W, int row, int k0) {
    const float* p = W + row * 32 + k0;
    short8 v;
#pragma unroll
    for (int e = 0; e < 8; ++e) v[e] = (short)to_bf16(p[e]);
    return v;
}

// Single-layer cell math, 7-trans variant:
//   r3 = rcp(Di*Df*Dg) serves i, f, AND tanh(g); r2 = rcp(Do*Dc) serves
//   sigma(o)*tanh(c) in one shot: h = (2-Dc)*r2.
static __device__ __forceinline__ unsigned short lstm_gates(floatx4 z, float& c) {
    float Di = 1.0f + ex2(z[0]);
    float Df = 1.0f + ex2(z[1]);
    float Dg = 1.0f + ex2(z[2]);
    float Do = 1.0f + ex2(z[3]);
    float m1 = Di * Df;            // Di*Df
    float tt = Df * Dg;            // Df*Dg
    float ss = Di * Dg;            // Di*Dg
    float r3 = rcpf(m1 * Dg);      // 1/(Di*Df*Dg)
    float i  = tt * r3;            // sigma(zi)
    float f  = ss * r3;            // sigma(zf)
    float tg = __builtin_fmaf(m1 + m1, r3, -1.0f);   // tanh(zg)
    c = __builtin_fmaf(f, c, i * tg);
    float Dc = 1.0f + ex2(N2LOG2E * c);
    float r2 = rcpf(Do * Dc);
    float h  = (2.0f - Dc) * r2;   // sigma(zo)*tanh(c)
    return cvt_bf16(h);
}

// Two-layer cell math, stage-interleaved, 7-trans per element.
static __device__ __forceinline__ void gates2(floatx4 z0, floatx4 z1,
                                              float& c0, float& c1,
                                              unsigned short& h0b, unsigned short& h1b) {
    float Di0 = 1.0f + ex2(z0[0]), Df0 = 1.0f + ex2(z0[1]);
    float Dg0 = 1.0f + ex2(z0[2]), Do0 = 1.0f + ex2(z0[3]);
    float Di1 = 1.0f + ex2(z1[0]), Df1 = 1.0f + ex2(z1[1]);
    float Dg1 = 1.0f + ex2(z1[2]), Do1 = 1.0f + ex2(z1[3]);
    float m10 = Di0 * Df0, tt0 = Df0 * Dg0, ss0 = Di0 * Dg0;
    float m11 = Di1 * Df1, tt1 = Df1 * Dg1, ss1 = Di1 * Dg1;
    float r30 = rcpf(m10 * Dg0);
    float r31 = rcpf(m11 * Dg1);
    float i0 = tt0 * r30, f0 = ss0 * r30;
    float i1 = tt1 * r31, f1 = ss1 * r31;
    float tg0 = __builtin_fmaf(m10 + m10, r30, -1.0f);
    float tg1 = __builtin_fmaf(m11 + m11, r31, -1.0f);
    c0 = __builtin_fmaf(f0, c0, i0 * tg0);
    c1 = __builtin_fmaf(f1, c1, i1 * tg1);
    float Dc0 = 1.0f + ex2(N2LOG2E * c0);
    float Dc1 = 1.0f + ex2(N2LOG2E * c1);
    float r20 = rcpf(Do0 * Dc0);
    float r21 = rcpf(Do1 * Dc1);
    h0b = cvt_bf16((2.0f - Dc0) * r20);
    h1b = cvt_bf16((2.0f - Dc1) * r21);
}

// Grid: 256 blocks (16-batch tiles). Block: 1024 threads = 16 waves = 4/SIMD.
// Work split per step:
//   A-waves (wv 0..7):  layer0 tile wv (1 MFMA) + layer1 tile wv (2 MFMA) — 14 trans
//   B-waves (wv 8..15): layer2 tile wv-8 (2 MFMA) — 7 trans
// A-waves carry the barrier tail -> priority 1 (set once); B-waves fill gaps.
// Software pipeline: iter k computes L0@k, L1@k-1, L2@k-2; ONE barrier/iter.
// h layout [buf][q-chunk][b][8 u16]: ds_read_b128 addr16 == laneid (conflict-free).
__global__ __launch_bounds__(1024, 1) void lstm_fused(
    const float* __restrict__ x,
    const float* __restrict__ Wih0, const float* __restrict__ Whh0,
    const float* __restrict__ bih0, const float* __restrict__ bhh0,
    const float* __restrict__ Wih1, const float* __restrict__ Whh1,
    const float* __restrict__ bih1, const float* __restrict__ bhh1,
    const float* __restrict__ Wih2, const float* __restrict__ Whh2,
    const float* __restrict__ bih2, const float* __restrict__ bhh2,
    const float* __restrict__ W2,   const float* __restrict__ b2,
    float* __restrict__ out)
{
    __shared__ float xs[MT][TT + 4];                // stride 516 floats
    __shared__ unsigned short h0s[2][4][MT][8];     // linear-in-lane b128 reads
    __shared__ unsigned short h1s[2][4][MT][8];
    __shared__ unsigned short h2s[2][4][MT][8];

    const int tid  = (int)threadIdx.x;
    const int wv   = tid >> 6;           // 0..15
    const int l    = tid & 63;
    const int b    = l & 15;
    const int q    = l >> 4;
    const bool aw  = (wv < 8);           // A-wave: L0+L1 ; B-wave: L2
    const int wj   = aw ? wv : (wv - 8); // job tile 0..7
    const int u    = 4 * wj + q;
    const int uc   = u >> 3, ue = u & 7;
    const int bt   = (int)blockIdx.x;
    const int arow = 16 * wj + b;
    const int k0   = q * 8;

    // critical-path waves get scheduler priority (persistent wave state)
    if (aw) __builtin_amdgcn_s_setprio(1);

    // ---- stage x tile [16][512] (2048 float4 / 1024 threads) ----
    {
        const floatx4* xg = (const floatx4*)(x + (size_t)bt * MT * TT);
#pragma unroll
        for (int j = 0; j < 2; ++j) {
            int idx = tid + j * 1024;
            int row = idx >> 7;
            int c4  = idx & 127;
            *(floatx4*)&xs[row][c4 * 4] = xg[idx];
        }
    }

    // ---- VGPR-resident pre-scaled weight fragments (per wave role) ----
    short8 whh0f = {}, wih1f = {}, whh1f = {}, wih2f = {}, whh2f = {};
    float wx0[4] = {0.f, 0.f, 0.f, 0.f};
    floatx4 bc0 = {0.f, 0.f, 0.f, 0.f}, bc1 = bc0, bc2 = bc0;
    if (aw) {
        whh0f = load_frag_perm(Whh0, arow, k0);
        wih1f = load_frag_perm(Wih1, arow, k0);
        whh1f = load_frag_perm(Whh1, arow, k0);
#pragma unroll
        for (int r = 0; r < 4; ++r) {
            int idx = r * 32 + u;
            float s = gate_scale(r);
            wx0[r] = s * Wih0[idx];
            bc0[r] = s * (bih0[idx] + bhh0[idx]);
            bc1[r] = s * (bih1[idx] + bhh1[idx]);
        }
    } else {
        wih2f = load_frag_perm(Wih2, arow, k0);
        whh2f = load_frag_perm(Whh2, arow, k0);
#pragma unroll
        for (int r = 0; r < 4; ++r) {
            int idx = r * 32 + u;
            float s = gate_scale(r);
            bc2[r] = s * (bih2[idx] + bhh2[idx]);
        }
    }

    short8 w2f = {};
    floatx4 b2c = {0.f, 0.f, 0.f, 0.f};
    if (wv < 2) {
        int r2 = 16 * wv + b;
        int rc = r2 < OUTN ? r2 : OUTN - 1;
        w2f = load_frag_plain(W2, rc, k0);
#pragma unroll
        for (int r = 0; r < 4; ++r) {
            int rr = 16 * wv + 4 * q + r;
            b2c[r] = (rr < OUTN) ? b2[rr] : 0.0f;
        }
    }

    float c0 = 0.f, c1 = 0.f, c2 = 0.f;

    __syncthreads();   // x staged

    // x-term folded into the MFMA C operand (off the post-MFMA critical path)
    auto bc0x = [&](float xv) {
        floatx4 c4v;
#pragma unroll
        for (int r = 0; r < 4; ++r) c4v[r] = __builtin_fmaf(xv, wx0[r], bc0[r]);
        return c4v;
    };

    // ---- prologue k=0: L0@0 (A only; h0(-1)=0 -> no MFMA) ----
    if (aw) {
        floatx4 z0 = bc0x(xs[b][0]);
        h0s[0][uc][b][ue] = lstm_gates(z0, c0);
    }
    __syncthreads();
    // ---- prologue k=1: L0@1 + L1@0 (A only; no whh1 term) ----
    if (aw) {
        short8 bh0 = *(const short8*)&h0s[0][q][b][0];
        floatx4 z0 = __builtin_amdgcn_mfma_f32_16x16x32_bf16(whh0f, bh0, bc0x(xs[b][1]), 0, 0, 0);
        floatx4 z1 = __builtin_amdgcn_mfma_f32_16x16x32_bf16(wih1f, bh0, bc1, 0, 0, 0);
        unsigned short h0b, h1b;
        gates2(z0, z1, c0, c1, h0b, h1b);
        h0s[1][uc][b][ue] = h0b;
        h1s[1][uc][b][ue] = h1b;
    }
    __syncthreads();
    // ---- prologue k=2: A: L0@2 + L1@1 (full) ; B: L2@0 (no whh2 term) ----
    if (aw) {
        short8 bh0 = *(const short8*)&h0s[1][q][b][0];
        short8 bh1 = *(const short8*)&h1s[1][q][b][0];
        floatx4 z0 = __builtin_amdgcn_mfma_f32_16x16x32_bf16(whh0f, bh0, bc0x(xs[b][2]), 0, 0, 0);
        floatx4 z1 = __builtin_amdgcn_mfma_f32_16x16x32_bf16(whh1f, bh1, bc1, 0, 0, 0);
        z1 = __builtin_amdgcn_mfma_f32_16x16x32_bf16(wih1f, bh0, z1, 0, 0, 0);
        unsigned short h0b, h1b;
        gates2(z0, z1, c0, c1, h0b, h1b);
        h0s[0][uc][b][ue] = h0b;
        h1s[0][uc][b][ue] = h1b;
    } else {
        short8 bh1 = *(const short8*)&h1s[1][q][b][0];
        floatx4 z2 = __builtin_amdgcn_mfma_f32_16x16x32_bf16(wih2f, bh1, bc2, 0, 0, 0);
        h2s[0][uc][b][ue] = lstm_gates(z2, c2);
    }
    __syncthreads();

    // ---- generic full step ----
    auto STEP = [&](float xv, int wb) {
        const int rb = wb ^ 1;
        if (aw) {
            short8 bh0 = *(const short8*)&h0s[rb][q][b][0];   // h0(t-1)
            short8 bh1 = *(const short8*)&h1s[rb][q][b][0];   // h1(t-2)
            floatx4 z0 = __builtin_amdgcn_mfma_f32_16x16x32_bf16(whh0f, bh0, bc0x(xv), 0, 0, 0);
            floatx4 z1 = __builtin_amdgcn_mfma_f32_16x16x32_bf16(whh1f, bh1, bc1, 0, 0, 0);
            z1 = __builtin_amdgcn_mfma_f32_16x16x32_bf16(wih1f, bh0, z1, 0, 0, 0);
            unsigned short h0b, h1b;
            gates2(z0, z1, c0, c1, h0b, h1b);
            h0s[wb][uc][b][ue] = h0b;
            h1s[wb][uc][b][ue] = h1b;
        } else {
            short8 bh1 = *(const short8*)&h1s[rb][q][b][0];   // h1(t-2) = h1(t2)
            short8 bh2 = *(const short8*)&h2s[rb][q][b][0];   // h2(t2-1)
            floatx4 z2 = __builtin_amdgcn_mfma_f32_16x16x32_bf16(whh2f, bh2, bc2, 0, 0, 0);
            z2 = __builtin_amdgcn_mfma_f32_16x16x32_bf16(wih2f, bh1, z2, 0, 0, 0);
            h2s[wb][uc][b][ue] = lstm_gates(z2, c2);
        }
        __syncthreads();
    };

    // ---- k=3: single full step; after: writes in buf 1 ----
    STEP(aw ? xs[b][3] : 0.0f, 1);

    // ---- main loop k=4..511: 127 x 4-step chunks, x via one b128 read (A only) ----
    for (int k = 4; k < TT; k += 4) {
        floatx4 xq = {0.f, 0.f, 0.f, 0.f};
        if (aw) xq = *(const floatx4*)&xs[b][k];
        STEP(xq[0], 0);
        STEP(xq[1], 1);
        STEP(xq[2], 0);
        STEP(xq[3], 1);
    }
    // state now: h0(511), h1(510) in buf 1; h2(509) in buf 1

    // ---- epilogue k=512: A: L1@511 ; B: L2@510 ----
    if (aw) {
        short8 bh0 = *(const short8*)&h0s[1][q][b][0];   // h0(511)
        short8 bh1 = *(const short8*)&h1s[1][q][b][0];   // h1(510)
        floatx4 z1 = __builtin_amdgcn_mfma_f32_16x16x32_bf16(whh1f, bh1, bc1, 0, 0, 0);
        z1 = __builtin_amdgcn_mfma_f32_16x16x32_bf16(wih1f, bh0, z1, 0, 0, 0);
        h1s[0][uc][b][ue] = lstm_gates(z1, c1);
    } else {
        short8 bh1 = *(const short8*)&h1s[1][q][b][0];   // h1(510)
        short8 bh2 = *(const short8*)&h2s[1][q][b][0];   // h2(509)
        floatx4 z2 = __builtin_amdgcn_mfma_f32_16x16x32_bf16(whh2f, bh2, bc2, 0, 0, 0);
        z2 = __builtin_amdgcn_mfma_f32_16x16x32_bf16(wih2f, bh1, z2, 0, 0, 0);
        h2s[0][uc][b][ue] = lstm_gates(z2, c2);
    }
    __syncthreads();
    // ---- epilogue k=513: B: L2@511 ----
    if (!aw) {
        short8 bh1 = *(const short8*)&h1s[0][q][b][0];   // h1(511)
        short8 bh2 = *(const short8*)&h2s[0][q][b][0];   // h2(510)
        floatx4 z2 = __builtin_amdgcn_mfma_f32_16x16x32_bf16(whh2f, bh2, bc2, 0, 0, 0);
        z2 = __builtin_amdgcn_mfma_f32_16x16x32_bf16(wih2f, bh1, z2, 0, 0, 0);
        h2s[1][uc][b][ue] = lstm_gates(z2, c2);
    }
    __syncthreads();

    // ---- out = h2(511) @ W2^T + b2 (waves 0,1), bias in C ----
    if (wv < 2) {
        short8 bh2 = *(const short8*)&h2s[1][q][b][0];
        floatx4 zo = __builtin_amdgcn_mfma_f32_16x16x32_bf16(w2f, bh2, b2c, 0, 0, 0);
#pragma unroll
        for (int r = 0; r < 4; ++r) {
            int rr = 16 * wv + 4 * q + r;
            if (rr < OUTN)
                out[(size_t)(bt * MT + b) * OUTN + rr] = zo[r];
        }
    }
}

extern "C" void kernel_launch(void* const* d_in, const int* in_sizes, int n_in,
                              void* d_out, int out_size, void* d_ws, size_t ws_size,
                              hipStream_t stream) {
    const float* x    = (const float*)d_in[0];
    const float* Wih0 = (const float*)d_in[1];
    const float* Whh0 = (const float*)d_in[2];
    const float* bih0 = (const float*)d_in[3];
    const float* bhh0 = (const float*)d_in[4];
    const float* Wih1 = (const float*)d_in[5];
    const float* Whh1 = (const float*)d_in[6];
    const float* bih1 = (const float*)d_in[7];
    const float* bhh1 = (const float*)d_in[8];
    const float* Wih2 = (const float*)d_in[9];
    const float* Whh2 = (const float*)d_in[10];
    const float* bih2 = (const float*)d_in[11];
    const float* bhh2 = (const float*)d_in[12];
    const float* W2   = (const float*)d_in[13];
    const float* b2   = (const float*)d_in[14];
    float* out = (float*)d_out;

    dim3 grid(4096 / MT);   // 256 blocks, 1/CU
    dim3 block(1024);       // 16 waves = 4/SIMD
    hipLaunchKernelGGL(lstm_fused, grid, block, 0, stream,
                       x, Wih0, Whh0, bih0, bhh0,
                       Wih1, Whh1, bih1, bhh1,
                       Wih2, Whh2, bih2, bhh2, W2, b2, out);
}